// Round 15
// baseline (645.768 us; speedup 1.0000x reference)
//
#include <hip/hip_runtime.h>
#include <stdint.h>

#define DEV __device__ __forceinline__
typedef unsigned short u16; typedef unsigned int u32; typedef unsigned long long u64;
typedef __attribute__((ext_vector_type(8))) short s8v;   // 8 x bf16 (4 VGPR)
typedef __attribute__((ext_vector_type(4))) float f4v;   // MFMA acc

#define Bb 512
#define Tt 256
#define Ff 64
#define Hh 128
#define Dd 192
#define L2E  1.4426950408889634f
#define L2E2 2.8853900817779268f

DEV u16 f2bf(float f){ u32 u = __builtin_bit_cast(u32, f); u32 r = (u + 0x7fffu + ((u>>16)&1u)) >> 16; return (u16)r; }
DEV float sigm(float x){ return __builtin_amdgcn_rcpf(1.0f + __expf(-x)); }
DEV float ex2(float x){ float r; asm("v_exp_f32 %0, %1" : "=v"(r) : "v"(x)); return r; }
// gate math on PRE-SCALED accumulators: i,f,o rows scaled by -log2e; g rows by +2log2e
DEV float sig2n(float y){ return __builtin_amdgcn_rcpf(1.0f + ex2(y)); }
DEV float th2 (float y){ return 1.0f - 2.0f*__builtin_amdgcn_rcpf(1.0f + ex2(y)); }
DEV u32 cvtpk(float lo, float hi){ u32 d; asm("v_cvt_pk_bf16_f32 %0, %1, %2" : "=v"(d) : "v"(lo), "v"(hi)); return d; }
DEV float blo(u32 q){ return __builtin_bit_cast(float, q<<16); }
DEV float bhi(u32 q){ return __builtin_bit_cast(float, q & 0xffff0000u); }

DEV f4v mfma16(s8v a, s8v b, f4v c){ return __builtin_amdgcn_mfma_f32_16x16x32_bf16(a, b, c, 0, 0, 0); }
DEV void barrier_lds(){ asm volatile("s_waitcnt lgkmcnt(0)\n\ts_barrier" ::: "memory"); }

// async global->LDS DMA, 16B/lane; lds base wave-uniform, global addr per-lane
DEV void dma16(const void* g, void* l){
  __builtin_amdgcn_global_load_lds((const __attribute__((address_space(1))) void*)g,
                                   (__attribute__((address_space(3))) void*)l, 16, 0, 0);
}

// fragment-linear hx layout: element (k,c) -> (k>>5)*512 + (((k>>3)&3)*16 + c)*8 + (k&7)
DEV int hxe2(int k, int c){ return (k>>5)*512 + (((k>>3)&3)*16 + c)*8 + (k&7); }

DEV s8v pack8s(const float* p, float sc){
  const float4 a = *(const float4*)p; const float4 b = *(const float4*)(p+4);
  s8v r; r[0]=(short)f2bf(a.x*sc); r[1]=(short)f2bf(a.y*sc); r[2]=(short)f2bf(a.z*sc); r[3]=(short)f2bf(a.w*sc);
  r[4]=(short)f2bf(b.x*sc); r[5]=(short)f2bf(b.y*sc); r[6]=(short)f2bf(b.z*sc); r[7]=(short)f2bf(b.w*sc); return r;
}
DEV s8v pack8(const float* p){ return pack8s(p, 1.0f); }
DEV u32 pk2(float a, float b){ return (u32)f2bf(a) | ((u32)f2bf(b)<<16); }

// 7-trans LSTM cell (r12/r13-validated): i,f,o accs pre-scaled by -log2e; g by +2log2e
#define CELL7_J(A0_, A1_, A2_, A3_, CSTJ_, HNJ_) { \
    float I_ = ex2(A0_), F_ = ex2(A1_), G_ = ex2(A2_), O_ = ex2(A3_); \
    float Aq = (1.0f + I_)*(G_ + 1.0f), Bq = 1.0f + F_; \
    float r1 = __builtin_amdgcn_rcpf(Aq*Bq); \
    float cn = r1*((CSTJ_)*Aq + Bq*(G_ - 1.0f)); \
    CSTJ_ = cn; \
    float CN_ = ex2(cn * L2E2); \
    float r2 = __builtin_amdgcn_rcpf((1.0f + O_)*(CN_ + 1.0f)); \
    HNJ_ = (CN_ - 1.0f)*r2; }

// ---------------- prelim: last_obs, x_last, score const term (pre-scaled by log2e) ---------
__global__ __launch_bounds__(64) void prelim_k(const float* __restrict__ x,
    const float* __restrict__ Watt, const float* __restrict__ batt,
    float* __restrict__ xlast, float* __restrict__ c0, int* __restrict__ lastobs)
{
  int b = blockIdx.x, tid = threadIdx.x;
  int cnt = 0;
  for (int it = 0; it < 4; ++it){
    int t = it*64 + tid;
    const float4* p = (const float4*)(x + ((size_t)b*Tt + t)*Ff);
    float s = 0.0f;
    #pragma unroll
    for (int q = 0; q < 16; ++q){ float4 v = p[q]; s += fabsf(v.x)+fabsf(v.y)+fabsf(v.z)+fabsf(v.w); }
    u64 m = __ballot(s != 0.0f);
    cnt += __popcll(m);
  }
  int last = cnt - 1;
  int li = (last < 0) ? (Tt-1) : last;
  float xl = x[((size_t)b*Tt + li)*Ff + tid];
  xlast[b*Ff + tid] = xl;
  float p = xl * Watt[Hh + tid];
  for (int off = 32; off; off >>= 1) p += __shfl_down(p, off);
  if (tid == 0){ c0[b] = (p + batt[0]) * L2E; lastobs[b] = last; }   // exp2-domain score
}

// ---------------- xw = ha @ W_ih_cs^T  (acc-init fragments, bf16; prescaled via WdIH) -------
__global__ __launch_bounds__(64) void xw_k(const u16* __restrict__ WdIH,
    const float* __restrict__ ha, u16* __restrict__ xwg)
{
  int lane = threadIdx.x, l15 = lane&15, l4 = lane>>4;
  int cg = blockIdx.x & 3, rm = blockIdx.x >> 2;   // rm < 96
  s8v af[6];
  #pragma unroll
  for (int kt=0;kt<6;++kt) af[kt] = *(const s8v*)(WdIH + (size_t)(rm*6+kt)*512 + lane*8);
  #pragma unroll
  for (int ct=0; ct<8; ++ct){
    int c = cg*128 + ct*16 + l15;
    f4v a = {0,0,0,0};
    #pragma unroll
    for (int kt=0;kt<6;++kt){
      s8v b = pack8(ha + (size_t)c*Dd + kt*32 + l4*8);
      a = mfma16(af[kt], b, a);
    }
    int bg = cg*8 + ct;
    int base = bg*24576 + rm*256 + l15*16 + l4*4;  // elements
    *(u32*)&xwg[base]   = pk2(a[0], a[1]);
    *(u32*)&xwg[base+2] = pk2(a[2], a[3]);
  }
}

// ---------------- encoder: LSTM (blocks 0..31) + decoder weight repack (blocks 32..607) -----
__global__ __launch_bounds__(512)
__attribute__((amdgpu_waves_per_eu(2,2)))
void enc_k(
    const float* __restrict__ x, const float* __restrict__ Whh, const float* __restrict__ Wih,
    const float* __restrict__ Wlong, const float* __restrict__ blong, const float* __restrict__ Watt,
    const float* __restrict__ xlast, const float* __restrict__ c0v, const int* __restrict__ lastobs,
    float* __restrict__ lp_out, float* __restrict__ ha,
    const float* __restrict__ Whhcs, const float* __restrict__ Wihcs,
    u16* __restrict__ Wd, u16* __restrict__ WdIH)
{
  if (blockIdx.x >= 32){
    // decoder weight repack: frag-major bf16, sign-folded prescale
    int idx = (blockIdx.x - 32)*512 + threadIdx.x;   // < 294912
    int j = idx & 7, lane2 = (idx>>3)&63;
    int f = idx>>9;                                  // < 576
    int kt = f % 6; int mtr = f/6;                   // mtr < 96
    int mt = mtr % 48, r = mtr/48;
    int ut = mt>>2, g = mt&3;
    int row = g*Dd + ut*16 + (lane2&15);
    int k = kt*32 + (lane2>>4)*8 + j;
    float sc = (g == 2) ? L2E2 : -L2E;
    size_t src = ((size_t)r*768 + row)*Dd + k;
    Wd[idx]   = f2bf(Whhcs[src] * sc);
    WdIH[idx] = f2bf(Wihcs[src] * sc);
    return;
  }
  __shared__ __align__(16) u16 hx[2][3072];
  __shared__ float sarr[2][16];
  const int tid = threadIdx.x, wid = tid>>6, lane = tid&63, l15 = lane&15, l4 = lane>>4;
  const int b0 = blockIdx.x*16;
  const int xrow = tid>>5, xc2 = (tid&31)*2;

  // gate weight fragments, sign-folded prescale (i,f,o: -log2e; g: +2log2e)
  s8v wf[4][6];
  #pragma unroll
  for (int mt = 0; mt < 4; ++mt){
    int gate = mt*Hh + wid*16 + l15;
    float sc = (mt == 2) ? L2E2 : -L2E;
    #pragma unroll
    for (int kt = 0; kt < 6; ++kt){
      int k0 = kt*32 + l4*8;
      if (kt < 4) wf[mt][kt] = pack8s(Whh + (size_t)gate*Hh + k0, sc);
      else        wf[mt][kt] = pack8s(Wih + (size_t)gate*Ff + (k0 - Hh), sc);
    }
  }
  s8v wfx[6];
  {
    s8v z = {0,0,0,0,0,0,0,0};
    #pragma unroll
    for (int kt = 0; kt < 6; ++kt) wfx[kt] = z;
    if (wid < 4){
      int f = wid*16 + l15;
      #pragma unroll
      for (int kt = 0; kt < 4; ++kt) wfx[kt] = pack8(Wlong + (size_t)f*Hh + kt*32 + l4*8);
    } else if (wid == 4 && l15 == 0){
      #pragma unroll
      for (int kt = 0; kt < 4; ++kt) wfx[kt] = pack8s(Watt + kt*32 + l4*8, L2E);  // exp2-domain
    }
  }
  float bl[4] = {0,0,0,0};
  if (wid < 4){
    #pragma unroll
    for (int j = 0; j < 4; ++j) bl[j] = blong[wid*16 + l4*4 + j];
  }
  const int   lastb = lastobs[b0 + l15];
  const float c0b   = c0v[b0 + l15];

  const int he0 = hxe2(wid*16 + l4*4, l15);          // h write (b64), element in buffer
  const int xe0 = hxe2(Hh + xc2, xrow);              // x write (b32)
  float* lpb = lp_out + ((size_t)(b0+l15)*Tt)*Ff + wid*16 + l4*4;

  // init hx[0]: h=0 (elements 0..2047), x_0
  ((u64*)hx[0])[tid] = 0ull;
  {
    float2 xv = *(const float2*)(x + ((size_t)(b0+xrow)*Tt + 0)*Ff + xc2);
    *(u32*)&hx[0][xe0] = cvtpk(xv.x, xv.y);
  }
  float2 xa = *(const float2*)(x + ((size_t)(b0+xrow)*Tt + 1)*Ff + xc2);
  float2 xb;
  __syncthreads();

  float cst[4] = {0,0,0,0}, hp[4] = {0,0,0,0}, hpp[4] = {0,0,0,0};
  float accA[4] = {0,0,0,0}, mrun = -3.0e38f, zrun = 0.0f;

#define ENC_STEP(T_, CURB_, NXTB_, XC_, XN_) { \
    const int t = (T_); \
    s8v bf[6]; \
    _Pragma("unroll") \
    for (int kt = 0; kt < 6; ++kt) \
      bf[kt] = *(const s8v*)&hx[CURB_][kt*512 + lane*8]; \
    { int tp = t + 2; if (tp > Tt-1) tp = Tt-1; \
      XN_ = *(const float2*)(x + ((size_t)(b0+xrow)*Tt + tp)*Ff + xc2); } \
    f4v acc0 = {0,0,0,0}, acc1 = {0,0,0,0}, acc2 = {0,0,0,0}, acc3 = {0,0,0,0}, accx = {0,0,0,0}; \
    _Pragma("unroll") \
    for (int kt = 0; kt < 6; ++kt){ \
      acc0 = mfma16(wf[0][kt], bf[kt], acc0); \
      acc1 = mfma16(wf[1][kt], bf[kt], acc1); \
      acc2 = mfma16(wf[2][kt], bf[kt], acc2); \
      acc3 = mfma16(wf[3][kt], bf[kt], acc3); \
    } \
    if (wid < 5){ \
      _Pragma("unroll") \
      for (int kt = 0; kt < 6; ++kt) accx = mfma16(wfx[kt], bf[kt], accx); \
    } \
    if (wid == 4 && l4 == 0) sarr[NXTB_][l15] = accx[0] + c0b; \
    float hnew[4]; \
    _Pragma("unroll") \
    for (int j = 0; j < 4; ++j){ \
      CELL7_J(acc0[j], acc1[j], acc2[j], acc3[j], cst[j], hnew[j]) \
    } \
    if (t >= 2){ \
      float sv = sarr[CURB_][l15]; \
      if (t-2 < lastb){ \
        float mn = fmaxf(mrun, sv); \
        float sc = ex2(mrun - mn); \
        float e  = ex2(sv - mn); \
        zrun = zrun*sc + e; \
        _Pragma("unroll") \
        for (int j = 0; j < 4; ++j) accA[j] = accA[j]*sc + e*hpp[j]; \
        mrun = mn; \
      } \
    } \
    _Pragma("unroll") \
    for (int j = 0; j < 4; ++j){ hpp[j] = hp[j]; hp[j] = hnew[j]; } \
    { u32 plo = cvtpk(hnew[0], hnew[1]), phi = cvtpk(hnew[2], hnew[3]); \
      *(u64*)&hx[NXTB_][he0] = (u64)plo | ((u64)phi<<32); } \
    if (t < Tt-1) *(u32*)&hx[NXTB_][xe0] = cvtpk(XC_.x, XC_.y); \
    if (wid < 4 && t >= 1){ \
      float4 v; v.x = accx[0]+bl[0]; v.y = accx[1]+bl[1]; v.z = accx[2]+bl[2]; v.w = accx[3]+bl[3]; \
      *(float4*)(lpb + (size_t)(t-1)*Ff) = v; \
    } \
    barrier_lds(); }

  for (int tp2 = 0; tp2 < 128; ++tp2){
    ENC_STEP(2*tp2,   0, 1, xa, xb)
    ENC_STEP(2*tp2+1, 1, 0, xb, xa)
  }
#undef ENC_STEP

  // epilogue (hx[0]=h_255, sarr[0]=s_254)
  {
    if (254 < lastb){
      float sv = sarr[0][l15];
      float mn = fmaxf(mrun, sv);
      float sc = ex2(mrun - mn);
      float e  = ex2(sv - mn);
      zrun = zrun*sc + e;
      #pragma unroll
      for (int j = 0; j < 4; ++j) accA[j] = accA[j]*sc + e*hpp[j];
      mrun = mn;
    }
    s8v bfE[4];
    #pragma unroll
    for (int kt = 0; kt < 4; ++kt)
      bfE[kt] = *(const s8v*)&hx[0][kt*512 + lane*8];
    if (wid < 4){
      f4v accx = {0,0,0,0};
      #pragma unroll
      for (int kt = 0; kt < 4; ++kt) accx = mfma16(wfx[kt], bfE[kt], accx);
      float4 v; v.x = accx[0]+bl[0]; v.y = accx[1]+bl[1]; v.z = accx[2]+bl[2]; v.w = accx[3]+bl[3];
      *(float4*)(lpb + (size_t)(Tt-1)*Ff) = v;
    }
    float inv = (zrun > 0.0f) ? __builtin_amdgcn_rcpf(zrun) : 0.0f;
    #pragma unroll
    for (int j = 0; j < 4; ++j)
      ha[(size_t)(b0 + l15)*Dd + wid*16 + l4*4 + j] = accA[j]*inv;
    __syncthreads();
    for (int q = tid; q < 16*Ff; q += 512){
      int r2 = q >> 6, f = q & 63;
      ha[(size_t)(b0 + r2)*Dd + Hh + f] = xlast[(b0 + r2)*Ff + f];
    }
  }
}

// ---------------- decoder v10: hybrid — kt0..2 via DMA ring, kt3..5 direct global->VGPR ----
__global__ __launch_bounds__(768)
__attribute__((amdgpu_waves_per_eu(3,3)))
void dec_k(const float* __restrict__ ha, const u16* __restrict__ Wd,
    const u16* __restrict__ xwg, const float* __restrict__ Wcs,
    const float* __restrict__ bcs, float* __restrict__ outs)
{
  __shared__ __align__(16) u16 hx[2][3072];          // 12 KB
  __shared__ __align__(16) u16 wstr[12*12*512];      // 144 KB: per-wave 12-slot stream ring
  __shared__ float red[2][12][16];
  const int tid = threadIdx.x, wid = tid>>6, lane = tid&63, l15 = lane&15, l4 = lane>>4;
  const int b0 = blockIdx.x*16;

  {
    int k = (tid>>4)*4, c = tid&15;
    float4 v = *(const float4*)(ha + (size_t)(b0+c)*Dd + k);
    int e = hxe2(k, c);
    *(u32*)&hx[0][e]   = cvtpk(v.x, v.y);
    *(u32*)&hx[0][e+2] = cvtpk(v.z, v.w);
  }
  // xw acc-init fragments in VGPRs (16 regs)
  u32 xwr[2][4][2];
  #pragma unroll
  for (int r = 0; r < 2; ++r)
    #pragma unroll
    for (int g = 0; g < 4; ++g){
      int base = blockIdx.x*24576 + (r*48 + wid*4 + g)*256 + l15*16 + l4*4;
      u64 q = *(const u64*)&xwg[base];
      xwr[r][g][0] = (u32)q; xwr[r][g][1] = (u32)(q>>32);
    }
  const int u0 = wid*16 + l4*4;
  float cst[4], wcs0[4], wcs1[4];
  #pragma unroll
  for (int j = 0; j < 4; ++j){
    cst[j]  = ha[(size_t)(b0+l15)*Dd + u0 + j];
    wcs0[j] = Wcs[u0 + j];
    wcs1[j] = Wcs[Dd + u0 + j];
  }
  const float bc0 = bcs[0], bc1 = bcs[1];
  const int he0 = hxe2(u0, l15);
  u16* const wring = &wstr[wid*12*512];
  __syncthreads();

// chunk for (risk R, kt, gate G): Wd[((R*48 + wid*4 + G)*6 + kt)*512 + lane*8], 1KB/wave
#define WSRC(R_, KT_, G_) (Wd + (size_t)(((R_)*48 + wid*4 + (G_))*6 + (KT_))*512 + lane*8)
// issue ring group (4 chunks) into slots (4*KTG+g)%12
#define ISSUE_G(RT_, KTT_, KTG_) { \
    dma16(WSRC(RT_, KTT_, 0), wring + ((4*(KTG_)+0)%12)*512); \
    dma16(WSRC(RT_, KTT_, 1), wring + ((4*(KTG_)+1)%12)*512); \
    dma16(WSRC(RT_, KTT_, 2), wring + ((4*(KTG_)+2)%12)*512); \
    dma16(WSRC(RT_, KTT_, 3), wring + ((4*(KTG_)+3)%12)*512); }
// load one group direct to VGPRs (16 regs, transient within step)
#define REGLD(R_, KT_, DST_) { \
    DST_[0] = *(const s8v*)WSRC(R_, KT_, 0); \
    DST_[1] = *(const s8v*)WSRC(R_, KT_, 1); \
    DST_[2] = *(const s8v*)WSRC(R_, KT_, 2); \
    DST_[3] = *(const s8v*)WSRC(R_, KT_, 3); }
// consume ring group: counted wait (8 ring-DMAs + 12 reg-loads younger), 4 slot reads + MFMA
#define GRP(CURB_, KTG_) { \
    asm volatile("s_waitcnt vmcnt(20)" ::: "memory"); \
    s8v q0 = *(const s8v*)(wring + ((4*(KTG_)+0)%12)*512 + lane*8); \
    s8v q1 = *(const s8v*)(wring + ((4*(KTG_)+1)%12)*512 + lane*8); \
    s8v q2 = *(const s8v*)(wring + ((4*(KTG_)+2)%12)*512 + lane*8); \
    s8v q3 = *(const s8v*)(wring + ((4*(KTG_)+3)%12)*512 + lane*8); \
    s8v bf = *(const s8v*)&hx[CURB_][(KTG_)*512 + lane*8]; \
    a0 = mfma16(q0, bf, a0); a1 = mfma16(q1, bf, a1); \
    a2 = mfma16(q2, bf, a2); a3 = mfma16(q3, bf, a3); }
// consume reg group
#define GRPR(CURB_, KT_, SRC_) { \
    s8v bf = *(const s8v*)&hx[CURB_][(KT_)*512 + lane*8]; \
    a0 = mfma16(SRC_[0], bf, a0); a1 = mfma16(SRC_[1], bf, a1); \
    a2 = mfma16(SRC_[2], bf, a2); a3 = mfma16(SRC_[3], bf, a3); }

#define XWI(R_) { \
    u32 lo, hi; \
    lo = xwr[R_][0][0]; hi = xwr[R_][0][1]; a0[0]=blo(lo); a0[1]=bhi(lo); a0[2]=blo(hi); a0[3]=bhi(hi); \
    lo = xwr[R_][1][0]; hi = xwr[R_][1][1]; a1[0]=blo(lo); a1[1]=bhi(lo); a1[2]=blo(hi); a1[3]=bhi(hi); \
    lo = xwr[R_][2][0]; hi = xwr[R_][2][1]; a2[0]=blo(lo); a2[1]=bhi(lo); a2[2]=blo(hi); a2[3]=bhi(hi); \
    lo = xwr[R_][3][0]; hi = xwr[R_][3][1]; a3[0]=blo(lo); a3[1]=bhi(lo); a3[2]=blo(hi); a3[3]=bhi(hi); }

#define CELLS(WCS_, NXTB_, PAR_, BC_, S_) { \
    float part = 0.0f, hn[4]; \
    _Pragma("unroll") for (int j = 0; j < 4; ++j){ \
      float si = sig2n(a0[j]), sf = sig2n(a1[j]); \
      float tg = th2(a2[j]),   so = sig2n(a3[j]); \
      float cn = sf*cst[j] + si*tg; \
      cst[j] = cn; \
      hn[j] = so * th2(cn * L2E2); \
      part += hn[j] * WCS_[j]; } \
    { u32 plo = cvtpk(hn[0], hn[1]), phi = cvtpk(hn[2], hn[3]); \
      *(u64*)&hx[NXTB_][he0] = (u64)plo | ((u64)phi<<32); } \
    part += __shfl_xor(part, 16); part += __shfl_xor(part, 32); \
    if (l4 == 0) red[PAR_][wid][l15] = part; \
    barrier_lds(); \
    if (tid < 16){ \
      float ss = BC_; \
      _Pragma("unroll") for (int q = 0; q < 12; ++q) ss += red[PAR_][q][tid]; \
      outs[(S_)*Bb + b0 + tid] = sigm(ss); } }

// one step: 12 reg loads (kt3..5) up front, 3 ring groups (kt0..2) with next-step re-issue,
// then reg-group consumption (compiler-counted waits), cell math.
#define DEC_STEP(R_, RN_, CURB_, NXTB_, WCS_, BC_, PAR_, S_) { \
    s8v r3[4], r4[4], r5[4]; \
    REGLD(R_, 3, r3) REGLD(R_, 4, r4) REGLD(R_, 5, r5) \
    f4v a0, a1, a2, a3; \
    XWI(R_) \
    GRP(CURB_, 0) ISSUE_G(RN_, 0, 0) \
    GRP(CURB_, 1) ISSUE_G(RN_, 1, 1) \
    GRP(CURB_, 2) ISSUE_G(RN_, 2, 2) \
    GRPR(CURB_, 3, r3) \
    GRPR(CURB_, 4, r4) \
    GRPR(CURB_, 5, r5) \
    CELLS(WCS_, NXTB_, PAR_, BC_, S_) }

  // prologue: issue step 0's ring groups kt0..2 (12 chunks -> slots 0..11)
  ISSUE_G(0, 0, 0); ISSUE_G(0, 1, 1); ISSUE_G(0, 2, 2);

  for (int sp = 0; sp < 32; ++sp){
    DEC_STEP(0, 1, 0, 1, wcs0, bc0, 0, sp*2)
    DEC_STEP(1, 0, 1, 0, wcs1, bc1, 1, sp*2+1)
  }
  asm volatile("s_waitcnt vmcnt(0)" ::: "memory");   // drain DMAs before endpgm
#undef WSRC
#undef ISSUE_G
#undef REGLD
#undef GRP
#undef GRPR
#undef XWI
#undef CELLS
#undef DEC_STEP
}

// ---------------- final softmax over 64 steps ----------------
__global__ __launch_bounds__(256) void fin_k(const float* __restrict__ outs, float* __restrict__ dout)
{
  int row = blockIdx.x*256 + threadIdx.x;
  float v[64]; float mx = -3.0e38f;
  #pragma unroll
  for (int s = 0; s < 64; ++s){ v[s] = outs[s*Bb + row]; mx = fmaxf(mx, v[s]); }
  float sum = 0.0f;
  #pragma unroll
  for (int s = 0; s < 64; ++s){ v[s] = __expf(v[s] - mx); sum += v[s]; }
  float inv = __builtin_amdgcn_rcpf(sum);
  float* p0 = dout + (size_t)Bb*Tt*Ff;
  float* p1 = p0 + Bb*32;
  #pragma unroll
  for (int j = 0; j < 32; ++j) p0[row*32 + j] = v[j]*inv;
  #pragma unroll
  for (int j = 0; j < 32; ++j) p1[row*32 + j] = v[32 + j]*inv;
}

extern "C" void kernel_launch(void* const* d_in, const int* in_sizes, int n_in,
                              void* d_out, int out_size, void* d_ws, size_t ws_size,
                              hipStream_t stream)
{
  const float* x      = (const float*)d_in[0];
  const float* Wih    = (const float*)d_in[1];
  const float* Whh    = (const float*)d_in[2];
  const float* Wlong  = (const float*)d_in[3];
  const float* blong  = (const float*)d_in[4];
  const float* Watt   = (const float*)d_in[5];
  const float* batt   = (const float*)d_in[6];
  const float* Wihcs  = (const float*)d_in[7];
  const float* Whhcs  = (const float*)d_in[8];
  const float* Wcs    = (const float*)d_in[9];
  const float* bcs    = (const float*)d_in[10];
  float* out = (float*)d_out;
  char* ws = (char*)d_ws;

  float* xlast   = (float*)ws;                   // 131072
  float* c0      = (float*)(ws + 131072);        // 2048
  int*   lastobs = (int*)  (ws + 133120);        // 2048
  float* ha      = (float*)(ws + 135168);        // 393216
  u16*   Wd      = (u16*)  (ws + 528384);        // 589824
  u16*   WdIH    = (u16*)  (ws + 1118208);       // 589824
  u16*   xwg     = (u16*)  (ws + 1708032);       // 1572864
  float* outs    = (float*)(ws + 3280896);       // 131072 -> ends 3411968 (proven footprint)

  prelim_k<<<Bb, 64, 0, stream>>>(x, Watt, batt, xlast, c0, lastobs);
  enc_k<<<608, 512, 0, stream>>>(x, Whh, Wih, Wlong, blong, Watt, xlast, c0, lastobs, out, ha,
                                 Whhcs, Wihcs, Wd, WdIH);
  xw_k<<<384, 64, 0, stream>>>(WdIH, ha, xwg);
  dec_k<<<32, 768, 0, stream>>>(ha, Wd, xwg, Wcs, bcs, outs);
  fin_k<<<2, 256, 0, stream>>>(outs, out);
}

// Round 16
// 527.886 us; speedup vs baseline: 1.2233x; 1.2233x over previous
//
#include <hip/hip_runtime.h>
#include <stdint.h>

#define DEV __device__ __forceinline__
typedef unsigned short u16; typedef unsigned int u32; typedef unsigned long long u64;
typedef __attribute__((ext_vector_type(8))) short s8v;   // 8 x bf16 (4 VGPR)
typedef __attribute__((ext_vector_type(4))) float f4v;   // MFMA acc

#define Bb 512
#define Tt 256
#define Ff 64
#define Hh 128
#define Dd 192
#define L2E  1.4426950408889634f
#define L2E2 2.8853900817779268f

DEV u16 f2bf(float f){ u32 u = __builtin_bit_cast(u32, f); u32 r = (u + 0x7fffu + ((u>>16)&1u)) >> 16; return (u16)r; }
DEV float bf2f(u16 h){ u32 u = ((u32)h)<<16; return __builtin_bit_cast(float, u); }
DEV float sigm(float x){ return __builtin_amdgcn_rcpf(1.0f + __expf(-x)); }
DEV float ex2(float x){ float r; asm("v_exp_f32 %0, %1" : "=v"(r) : "v"(x)); return r; }
// gate math on PRE-SCALED accumulators: i,f,o rows scaled by -log2e; g rows by +2log2e
DEV float sig2n(float y){ return __builtin_amdgcn_rcpf(1.0f + ex2(y)); }
DEV float th2 (float y){ return 1.0f - 2.0f*__builtin_amdgcn_rcpf(1.0f + ex2(y)); }
DEV u32 cvtpk(float lo, float hi){ u32 d; asm("v_cvt_pk_bf16_f32 %0, %1, %2" : "=v"(d) : "v"(lo), "v"(hi)); return d; }
DEV float blo(u32 q){ return __builtin_bit_cast(float, q<<16); }
DEV float bhi(u32 q){ return __builtin_bit_cast(float, q & 0xffff0000u); }

DEV f4v mfma16(s8v a, s8v b, f4v c){ return __builtin_amdgcn_mfma_f32_16x16x32_bf16(a, b, c, 0, 0, 0); }
DEV void barrier_lds(){ asm volatile("s_waitcnt lgkmcnt(0)\n\ts_barrier" ::: "memory"); }

// async global->LDS DMA, 16B/lane; lds base wave-uniform, global addr per-lane
DEV void dma16(const void* g, void* l){
  __builtin_amdgcn_global_load_lds((const __attribute__((address_space(1))) void*)g,
                                   (__attribute__((address_space(3))) void*)l, 16, 0, 0);
}

// fragment-linear hx layout: element (k,c) -> (k>>5)*512 + (((k>>3)&3)*16 + c)*8 + (k&7)
DEV int hxe2(int k, int c){ return (k>>5)*512 + (((k>>3)&3)*16 + c)*8 + (k&7); }

DEV s8v pack8s(const float* p, float sc){
  const float4 a = *(const float4*)p; const float4 b = *(const float4*)(p+4);
  s8v r; r[0]=(short)f2bf(a.x*sc); r[1]=(short)f2bf(a.y*sc); r[2]=(short)f2bf(a.z*sc); r[3]=(short)f2bf(a.w*sc);
  r[4]=(short)f2bf(b.x*sc); r[5]=(short)f2bf(b.y*sc); r[6]=(short)f2bf(b.z*sc); r[7]=(short)f2bf(b.w*sc); return r;
}
DEV s8v pack8(const float* p){ return pack8s(p, 1.0f); }
DEV u32 pk2(float a, float b){ return (u32)f2bf(a) | ((u32)f2bf(b)<<16); }

// 7-trans LSTM cell (r12/r13-validated): i,f,o accs pre-scaled by -log2e; g by +2log2e
#define CELL7_J(A0_, A1_, A2_, A3_, CSTJ_, HNJ_) { \
    float I_ = ex2(A0_), F_ = ex2(A1_), G_ = ex2(A2_), O_ = ex2(A3_); \
    float Aq = (1.0f + I_)*(G_ + 1.0f), Bq = 1.0f + F_; \
    float r1 = __builtin_amdgcn_rcpf(Aq*Bq); \
    float cn = r1*((CSTJ_)*Aq + Bq*(G_ - 1.0f)); \
    CSTJ_ = cn; \
    float CN_ = ex2(cn * L2E2); \
    float r2 = __builtin_amdgcn_rcpf((1.0f + O_)*(CN_ + 1.0f)); \
    HNJ_ = (CN_ - 1.0f)*r2; }

// ---------------- prelim: last_obs, x_last, score const term (pre-scaled by log2e) ---------
__global__ __launch_bounds__(64) void prelim_k(const float* __restrict__ x,
    const float* __restrict__ Watt, const float* __restrict__ batt,
    float* __restrict__ xlast, float* __restrict__ c0, int* __restrict__ lastobs)
{
  int b = blockIdx.x, tid = threadIdx.x;
  int cnt = 0;
  for (int it = 0; it < 4; ++it){
    int t = it*64 + tid;
    const float4* p = (const float4*)(x + ((size_t)b*Tt + t)*Ff);
    float s = 0.0f;
    #pragma unroll
    for (int q = 0; q < 16; ++q){ float4 v = p[q]; s += fabsf(v.x)+fabsf(v.y)+fabsf(v.z)+fabsf(v.w); }
    u64 m = __ballot(s != 0.0f);
    cnt += __popcll(m);
  }
  int last = cnt - 1;
  int li = (last < 0) ? (Tt-1) : last;
  float xl = x[((size_t)b*Tt + li)*Ff + tid];
  xlast[b*Ff + tid] = xl;
  float p = xl * Watt[Hh + tid];
  for (int off = 32; off; off >>= 1) p += __shfl_down(p, off);
  if (tid == 0){ c0[b] = (p + batt[0]) * L2E; lastobs[b] = last; }   // exp2-domain score
}

// ---------------- xw = ha @ W_ih_cs^T  (acc-init fragments, bf16; prescaled via WdIH) -------
__global__ __launch_bounds__(64) void xw_k(const u16* __restrict__ WdIH,
    const float* __restrict__ ha, u16* __restrict__ xwg)
{
  int lane = threadIdx.x, l15 = lane&15, l4 = lane>>4;
  int cg = blockIdx.x & 3, rm = blockIdx.x >> 2;   // rm < 96
  s8v af[6];
  #pragma unroll
  for (int kt=0;kt<6;++kt) af[kt] = *(const s8v*)(WdIH + (size_t)(rm*6+kt)*512 + lane*8);
  #pragma unroll
  for (int ct=0; ct<8; ++ct){
    int c = cg*128 + ct*16 + l15;
    f4v a = {0,0,0,0};
    #pragma unroll
    for (int kt=0;kt<6;++kt){
      s8v b = pack8(ha + (size_t)c*Dd + kt*32 + l4*8);
      a = mfma16(af[kt], b, a);
    }
    int bg = cg*8 + ct;
    int base = bg*24576 + rm*256 + l15*16 + l4*4;  // elements
    *(u32*)&xwg[base]   = pk2(a[0], a[1]);
    *(u32*)&xwg[base+2] = pk2(a[2], a[3]);
  }
}

// ---------------- encoder: LSTM (blocks 0..31) + decoder weight repack (blocks 32..607) -----
__global__ __launch_bounds__(512)
__attribute__((amdgpu_waves_per_eu(2,2)))
void enc_k(
    const float* __restrict__ x, const float* __restrict__ Whh, const float* __restrict__ Wih,
    const float* __restrict__ Wlong, const float* __restrict__ blong, const float* __restrict__ Watt,
    const float* __restrict__ xlast, const float* __restrict__ c0v, const int* __restrict__ lastobs,
    float* __restrict__ lp_out, float* __restrict__ ha,
    const float* __restrict__ Whhcs, const float* __restrict__ Wihcs,
    u16* __restrict__ Wd, u16* __restrict__ WdIH)
{
  if (blockIdx.x >= 32){
    // decoder weight repack: frag-major bf16, sign-folded prescale
    int idx = (blockIdx.x - 32)*512 + threadIdx.x;   // < 294912
    int j = idx & 7, lane2 = (idx>>3)&63;
    int f = idx>>9;                                  // < 576
    int kt = f % 6; int mtr = f/6;                   // mtr < 96
    int mt = mtr % 48, r = mtr/48;
    int ut = mt>>2, g = mt&3;
    int row = g*Dd + ut*16 + (lane2&15);
    int k = kt*32 + (lane2>>4)*8 + j;
    float sc = (g == 2) ? L2E2 : -L2E;
    size_t src = ((size_t)r*768 + row)*Dd + k;
    Wd[idx]   = f2bf(Whhcs[src] * sc);
    WdIH[idx] = f2bf(Wihcs[src] * sc);
    return;
  }
  __shared__ __align__(16) u16 hx[2][3072];
  __shared__ float sarr[2][16];
  const int tid = threadIdx.x, wid = tid>>6, lane = tid&63, l15 = lane&15, l4 = lane>>4;
  const int b0 = blockIdx.x*16;
  const int xrow = tid>>5, xc2 = (tid&31)*2;

  // gate weight fragments, sign-folded prescale (i,f,o: -log2e; g: +2log2e)
  s8v wf[4][6];
  #pragma unroll
  for (int mt = 0; mt < 4; ++mt){
    int gate = mt*Hh + wid*16 + l15;
    float sc = (mt == 2) ? L2E2 : -L2E;
    #pragma unroll
    for (int kt = 0; kt < 6; ++kt){
      int k0 = kt*32 + l4*8;
      if (kt < 4) wf[mt][kt] = pack8s(Whh + (size_t)gate*Hh + k0, sc);
      else        wf[mt][kt] = pack8s(Wih + (size_t)gate*Ff + (k0 - Hh), sc);
    }
  }
  s8v wfx[6];
  {
    s8v z = {0,0,0,0,0,0,0,0};
    #pragma unroll
    for (int kt = 0; kt < 6; ++kt) wfx[kt] = z;
    if (wid < 4){
      int f = wid*16 + l15;
      #pragma unroll
      for (int kt = 0; kt < 4; ++kt) wfx[kt] = pack8(Wlong + (size_t)f*Hh + kt*32 + l4*8);
    } else if (wid == 4 && l15 == 0){
      #pragma unroll
      for (int kt = 0; kt < 4; ++kt) wfx[kt] = pack8s(Watt + kt*32 + l4*8, L2E);  // exp2-domain
    }
  }
  float bl[4] = {0,0,0,0};
  if (wid < 4){
    #pragma unroll
    for (int j = 0; j < 4; ++j) bl[j] = blong[wid*16 + l4*4 + j];
  }
  const int   lastb = lastobs[b0 + l15];
  const float c0b   = c0v[b0 + l15];

  const int he0 = hxe2(wid*16 + l4*4, l15);          // h write (b64), element in buffer
  const int xe0 = hxe2(Hh + xc2, xrow);              // x write (b32)
  float* lpb = lp_out + ((size_t)(b0+l15)*Tt)*Ff + wid*16 + l4*4;

  // init hx[0]: h=0 (elements 0..2047), x_0
  ((u64*)hx[0])[tid] = 0ull;
  {
    float2 xv = *(const float2*)(x + ((size_t)(b0+xrow)*Tt + 0)*Ff + xc2);
    *(u32*)&hx[0][xe0] = cvtpk(xv.x, xv.y);
  }
  float2 xa = *(const float2*)(x + ((size_t)(b0+xrow)*Tt + 1)*Ff + xc2);
  float2 xb;
  __syncthreads();

  float cst[4] = {0,0,0,0}, hp[4] = {0,0,0,0}, hpp[4] = {0,0,0,0};
  float accA[4] = {0,0,0,0}, mrun = -3.0e38f, zrun = 0.0f;

#define ENC_STEP(T_, CURB_, NXTB_, XC_, XN_) { \
    const int t = (T_); \
    s8v bf[6]; \
    _Pragma("unroll") \
    for (int kt = 0; kt < 6; ++kt) \
      bf[kt] = *(const s8v*)&hx[CURB_][kt*512 + lane*8]; \
    { int tp = t + 2; if (tp > Tt-1) tp = Tt-1; \
      XN_ = *(const float2*)(x + ((size_t)(b0+xrow)*Tt + tp)*Ff + xc2); } \
    f4v acc0 = {0,0,0,0}, acc1 = {0,0,0,0}, acc2 = {0,0,0,0}, acc3 = {0,0,0,0}, accx = {0,0,0,0}; \
    _Pragma("unroll") \
    for (int kt = 0; kt < 6; ++kt){ \
      acc0 = mfma16(wf[0][kt], bf[kt], acc0); \
      acc1 = mfma16(wf[1][kt], bf[kt], acc1); \
      acc2 = mfma16(wf[2][kt], bf[kt], acc2); \
      acc3 = mfma16(wf[3][kt], bf[kt], acc3); \
    } \
    if (wid < 5){ \
      _Pragma("unroll") \
      for (int kt = 0; kt < 6; ++kt) accx = mfma16(wfx[kt], bf[kt], accx); \
    } \
    if (wid == 4 && l4 == 0) sarr[NXTB_][l15] = accx[0] + c0b; \
    float hnew[4]; \
    _Pragma("unroll") \
    for (int j = 0; j < 4; ++j){ \
      CELL7_J(acc0[j], acc1[j], acc2[j], acc3[j], cst[j], hnew[j]) \
    } \
    if (t >= 2){ \
      float sv = sarr[CURB_][l15]; \
      if (t-2 < lastb){ \
        float mn = fmaxf(mrun, sv); \
        float sc = ex2(mrun - mn); \
        float e  = ex2(sv - mn); \
        zrun = zrun*sc + e; \
        _Pragma("unroll") \
        for (int j = 0; j < 4; ++j) accA[j] = accA[j]*sc + e*hpp[j]; \
        mrun = mn; \
      } \
    } \
    _Pragma("unroll") \
    for (int j = 0; j < 4; ++j){ hpp[j] = hp[j]; hp[j] = hnew[j]; } \
    { u32 plo = cvtpk(hnew[0], hnew[1]), phi = cvtpk(hnew[2], hnew[3]); \
      *(u64*)&hx[NXTB_][he0] = (u64)plo | ((u64)phi<<32); } \
    if (t < Tt-1) *(u32*)&hx[NXTB_][xe0] = cvtpk(XC_.x, XC_.y); \
    if (wid < 4 && t >= 1){ \
      float4 v; v.x = accx[0]+bl[0]; v.y = accx[1]+bl[1]; v.z = accx[2]+bl[2]; v.w = accx[3]+bl[3]; \
      *(float4*)(lpb + (size_t)(t-1)*Ff) = v; \
    } \
    barrier_lds(); }

  for (int tp2 = 0; tp2 < 128; ++tp2){
    ENC_STEP(2*tp2,   0, 1, xa, xb)
    ENC_STEP(2*tp2+1, 1, 0, xb, xa)
  }
#undef ENC_STEP

  // epilogue (hx[0]=h_255, sarr[0]=s_254)
  {
    if (254 < lastb){
      float sv = sarr[0][l15];
      float mn = fmaxf(mrun, sv);
      float sc = ex2(mrun - mn);
      float e  = ex2(sv - mn);
      zrun = zrun*sc + e;
      #pragma unroll
      for (int j = 0; j < 4; ++j) accA[j] = accA[j]*sc + e*hpp[j];
      mrun = mn;
    }
    s8v bfE[4];
    #pragma unroll
    for (int kt = 0; kt < 4; ++kt)
      bfE[kt] = *(const s8v*)&hx[0][kt*512 + lane*8];
    if (wid < 4){
      f4v accx = {0,0,0,0};
      #pragma unroll
      for (int kt = 0; kt < 4; ++kt) accx = mfma16(wfx[kt], bfE[kt], accx);
      float4 v; v.x = accx[0]+bl[0]; v.y = accx[1]+bl[1]; v.z = accx[2]+bl[2]; v.w = accx[3]+bl[3];
      *(float4*)(lpb + (size_t)(Tt-1)*Ff) = v;
    }
    float inv = (zrun > 0.0f) ? __builtin_amdgcn_rcpf(zrun) : 0.0f;
    #pragma unroll
    for (int j = 0; j < 4; ++j)
      ha[(size_t)(b0 + l15)*Dd + wid*16 + l4*4 + j] = accA[j]*inv;
    __syncthreads();
    for (int q = tid; q < 16*Ff; q += 512){
      int r2 = q >> 6, f = q & 63;
      ha[(size_t)(b0 + r2)*Dd + Hh + f] = xlast[(b0 + r2)*Ff + f];
    }
  }
}

// ---------------- decoder v9 (r11/r14-exact loop) + fused final softmax ---------------------
__global__ __launch_bounds__(768, 3)
void dec_k(const float* __restrict__ ha, const u16* __restrict__ Wd,
    const u16* __restrict__ xwg, const float* __restrict__ Wcs,
    const float* __restrict__ bcs, float* __restrict__ dout)
{
  __shared__ __align__(16) u16 hx[2][3072];          // 12 KB
  __shared__ __align__(16) u16 wstr[12*12*512];      // 144 KB: per-wave 12-slot stream ring
  __shared__ float red[2][12][16];
  __shared__ u16 outl[64*16];                        // 2 KB: per-step sigmoids (bf16)
  const int tid = threadIdx.x, wid = tid>>6, lane = tid&63, l15 = lane&15, l4 = lane>>4;
  const int b0 = blockIdx.x*16;

  {
    int k = (tid>>4)*4, c = tid&15;
    float4 v = *(const float4*)(ha + (size_t)(b0+c)*Dd + k);
    int e = hxe2(k, c);
    *(u32*)&hx[0][e]   = cvtpk(v.x, v.y);
    *(u32*)&hx[0][e+2] = cvtpk(v.z, v.w);
  }
  // xw acc-init fragments in VGPRs (16 regs)
  u32 xwr[2][4][2];
  #pragma unroll
  for (int r = 0; r < 2; ++r)
    #pragma unroll
    for (int g = 0; g < 4; ++g){
      int base = blockIdx.x*24576 + (r*48 + wid*4 + g)*256 + l15*16 + l4*4;
      u64 q = *(const u64*)&xwg[base];
      xwr[r][g][0] = (u32)q; xwr[r][g][1] = (u32)(q>>32);
    }
  const int u0 = wid*16 + l4*4;
  float cst[4], wcs0[4], wcs1[4];
  #pragma unroll
  for (int j = 0; j < 4; ++j){
    cst[j]  = ha[(size_t)(b0+l15)*Dd + u0 + j];
    wcs0[j] = Wcs[u0 + j];
    wcs1[j] = Wcs[Dd + u0 + j];
  }
  const float bc0 = bcs[0], bc1 = bcs[1];
  const int he0 = hxe2(u0, l15);
  u16* const wring = &wstr[wid*12*512];
  __syncthreads();

// chunk for (risk R, kt, gate G): Wd[((R*48 + wid*4 + G)*6 + kt)*512 + lane*8], 1KB/wave
#define WSRC(R_, KT_, G_) (Wd + (size_t)(((R_)*48 + wid*4 + (G_))*6 + (KT_))*512 + lane*8)
// issue one 4-chunk group into slots (4*KTG+g)%12 (the group just consumed)
#define ISSUE_G(RT_, KTT_, KTG_) { \
    dma16(WSRC(RT_, KTT_, 0), wring + ((4*(KTG_)+0)%12)*512); \
    dma16(WSRC(RT_, KTT_, 1), wring + ((4*(KTG_)+1)%12)*512); \
    dma16(WSRC(RT_, KTT_, 2), wring + ((4*(KTG_)+2)%12)*512); \
    dma16(WSRC(RT_, KTT_, 3), wring + ((4*(KTG_)+3)%12)*512); }
// consume one group: counted wait (8 younger DMAs stay in flight), 4 weight reads + bf + MFMA
#define GRP(CURB_, KTG_) { \
    asm volatile("s_waitcnt vmcnt(8)" ::: "memory"); \
    s8v q0 = *(const s8v*)(wring + ((4*(KTG_)+0)%12)*512 + lane*8); \
    s8v q1 = *(const s8v*)(wring + ((4*(KTG_)+1)%12)*512 + lane*8); \
    s8v q2 = *(const s8v*)(wring + ((4*(KTG_)+2)%12)*512 + lane*8); \
    s8v q3 = *(const s8v*)(wring + ((4*(KTG_)+3)%12)*512 + lane*8); \
    s8v bf = *(const s8v*)&hx[CURB_][(KTG_)*512 + lane*8]; \
    a0 = mfma16(q0, bf, a0); a1 = mfma16(q1, bf, a1); \
    a2 = mfma16(q2, bf, a2); a3 = mfma16(q3, bf, a3); }

#define XWI(R_) { \
    u32 lo, hi; \
    lo = xwr[R_][0][0]; hi = xwr[R_][0][1]; a0[0]=blo(lo); a0[1]=bhi(lo); a0[2]=blo(hi); a0[3]=bhi(hi); \
    lo = xwr[R_][1][0]; hi = xwr[R_][1][1]; a1[0]=blo(lo); a1[1]=bhi(lo); a1[2]=blo(hi); a1[3]=bhi(hi); \
    lo = xwr[R_][2][0]; hi = xwr[R_][2][1]; a2[0]=blo(lo); a2[1]=bhi(lo); a2[2]=blo(hi); a2[3]=bhi(hi); \
    lo = xwr[R_][3][0]; hi = xwr[R_][3][1]; a3[0]=blo(lo); a3[1]=bhi(lo); a3[2]=blo(hi); a3[3]=bhi(hi); }

#define CELLS(WCS_, NXTB_, PAR_, BC_, S_) { \
    float part = 0.0f, hn[4]; \
    _Pragma("unroll") for (int j = 0; j < 4; ++j){ \
      float si = sig2n(a0[j]), sf = sig2n(a1[j]); \
      float tg = th2(a2[j]),   so = sig2n(a3[j]); \
      float cn = sf*cst[j] + si*tg; \
      cst[j] = cn; \
      hn[j] = so * th2(cn * L2E2); \
      part += hn[j] * WCS_[j]; } \
    { u32 plo = cvtpk(hn[0], hn[1]), phi = cvtpk(hn[2], hn[3]); \
      *(u64*)&hx[NXTB_][he0] = (u64)plo | ((u64)phi<<32); } \
    part += __shfl_xor(part, 16); part += __shfl_xor(part, 32); \
    if (l4 == 0) red[PAR_][wid][l15] = part; \
    barrier_lds(); \
    if (tid < 16){ \
      float ss = BC_; \
      _Pragma("unroll") for (int q = 0; q < 12; ++q) ss += red[PAR_][q][tid]; \
      outl[(S_)*16 + tid] = f2bf(sigm(ss)); } }

// one step: 6 kt-groups; issue 3 groups ahead (ktg 0-2 -> same step kt3-5; ktg 3-5 -> next step kt0-2)
#define DEC_STEP(R_, RN_, CURB_, NXTB_, WCS_, BC_, PAR_, S_) { \
    f4v a0, a1, a2, a3; \
    XWI(R_) \
    GRP(CURB_, 0) ISSUE_G(R_,  3, 0) \
    GRP(CURB_, 1) ISSUE_G(R_,  4, 1) \
    GRP(CURB_, 2) ISSUE_G(R_,  5, 2) \
    GRP(CURB_, 3) ISSUE_G(RN_, 0, 3) \
    GRP(CURB_, 4) ISSUE_G(RN_, 1, 4) \
    GRP(CURB_, 5) ISSUE_G(RN_, 2, 5) \
    CELLS(WCS_, NXTB_, PAR_, BC_, S_) }

  // prologue: issue step 0's kt0..2 (12 chunks -> slots 0..11)
  ISSUE_G(0, 0, 0); ISSUE_G(0, 1, 1); ISSUE_G(0, 2, 2);

  for (int sp = 0; sp < 32; ++sp){
    DEC_STEP(0, 1, 0, 1, wcs0, bc0, 0, sp*2)
    DEC_STEP(1, 0, 1, 0, wcs1, bc1, 1, sp*2+1)
  }
  asm volatile("s_waitcnt vmcnt(0)" ::: "memory");   // drain DMAs before epilogue

  // fused final softmax over the 64 per-step sigmoids (thread tid<16 owns row b0+tid;
  // all outl[s*16+tid] were written by this same thread -> no barrier needed)
  if (tid < 16){
    const int row = b0 + tid;
    float mx = -3.0e38f;
    #pragma unroll
    for (int s = 0; s < 64; ++s) mx = fmaxf(mx, bf2f(outl[s*16 + tid]));
    float sum = 0.0f;
    #pragma unroll
    for (int s = 0; s < 64; ++s) sum += __expf(bf2f(outl[s*16 + tid]) - mx);
    float inv = __builtin_amdgcn_rcpf(sum);
    float* p0 = dout + (size_t)Bb*Tt*Ff + (size_t)row*32;
    float* p1 = p0 + (size_t)Bb*32;
    #pragma unroll
    for (int s = 0; s < 32; ++s) p0[s] = __expf(bf2f(outl[s*16 + tid]) - mx)*inv;
    #pragma unroll
    for (int s = 0; s < 32; ++s) p1[s] = __expf(bf2f(outl[(32+s)*16 + tid]) - mx)*inv;
  }
#undef WSRC
#undef ISSUE_G
#undef GRP
#undef XWI
#undef CELLS
#undef DEC_STEP
}

extern "C" void kernel_launch(void* const* d_in, const int* in_sizes, int n_in,
                              void* d_out, int out_size, void* d_ws, size_t ws_size,
                              hipStream_t stream)
{
  const float* x      = (const float*)d_in[0];
  const float* Wih    = (const float*)d_in[1];
  const float* Whh    = (const float*)d_in[2];
  const float* Wlong  = (const float*)d_in[3];
  const float* blong  = (const float*)d_in[4];
  const float* Watt   = (const float*)d_in[5];
  const float* batt   = (const float*)d_in[6];
  const float* Wihcs  = (const float*)d_in[7];
  const float* Whhcs  = (const float*)d_in[8];
  const float* Wcs    = (const float*)d_in[9];
  const float* bcs    = (const float*)d_in[10];
  float* out = (float*)d_out;
  char* ws = (char*)d_ws;

  float* xlast   = (float*)ws;                   // 131072
  float* c0      = (float*)(ws + 131072);        // 2048
  int*   lastobs = (int*)  (ws + 133120);        // 2048
  float* ha      = (float*)(ws + 135168);        // 393216
  u16*   Wd      = (u16*)  (ws + 528384);        // 589824
  u16*   WdIH    = (u16*)  (ws + 1118208);       // 589824
  u16*   xwg     = (u16*)  (ws + 1708032);       // 1572864 -> ends 3280896 (within proven footprint)

  prelim_k<<<Bb, 64, 0, stream>>>(x, Watt, batt, xlast, c0, lastobs);
  enc_k<<<608, 512, 0, stream>>>(x, Whh, Wih, Wlong, blong, Watt, xlast, c0, lastobs, out, ha,
                                 Whhcs, Wihcs, Wd, WdIH);
  xw_k<<<384, 64, 0, stream>>>(WdIH, ha, xwg);
  dec_k<<<32, 768, 0, stream>>>(ha, Wd, xwg, Wcs, bcs, out);
}